// Round 1
// baseline (394.323 us; speedup 1.0000x reference)
//
#include <hip/hip_runtime.h>
#include <math.h>

#define EPSF 1e-8f
#define SINH_MAXF 11.090354888959125f
#define IMAGE_ALPHA 0.25f
#define TEXT_ALPHA (1.0f/0.6f)
#define LOGIT_SCALE (1.0f/0.07f)
#define ENTAIL_WEIGHT 0.2f
#define NCLS 151
#define DIM 64

// workspace layout (floats)
#define ACC_OFF 0      // [0]=sum_nll, [1]=sum_ent, [2]=valid_count  (16 floats reserved)
#define TXT_OFF 16                     // 151*64 proto vectors on hyperboloid
#define YT_OFF  (16 + NCLS*DIM)        // y_time per class
#define XN_OFF  (YT_OFF + NCLS)        // ||txt|| per class
#define AP_OFF  (XN_OFF + NCLS)        // half-aperture per class

__global__ void proto_kernel(const float* __restrict__ protos, float* __restrict__ ws) {
    int c = blockIdx.x;
    int d = threadIdx.x;
    float v = protos[c * DIM + d] * TEXT_ALPHA;
    float n2 = v * v;
    #pragma unroll
    for (int m = 32; m >= 1; m >>= 1) n2 += __shfl_xor(n2, m, 64);
    float rc = sqrtf(n2);
    float sh = sinhf(fminf(fmaxf(rc, EPSF), SINH_MAXF));
    float sc = sh / fmaxf(rc, EPSF);
    ws[TXT_OFF + c * DIM + d] = sc * v;
    if (d == 0) {
        float xn = sc * rc;                     // ||txt_c||
        ws[YT_OFF + c] = sqrtf(1.0f + xn * xn); // y_time
        ws[XN_OFF + c] = xn;
        float asin_in = 2.0f * 0.1f / (xn + EPSF);
        asin_in = fminf(fmaxf(asin_in, -1.0f + EPSF), 1.0f - EPSF);
        ws[AP_OFF + c] = asinf(asin_in);
    }
}

__global__ __launch_bounds__(256) void main_kernel(
    const float* __restrict__ feats, const int* __restrict__ labels,
    const unsigned char* __restrict__ mask, const float* __restrict__ wsro,
    float* acc)
{
    int p = blockIdx.x * 256 + threadIdx.x;

    // ---- image exp_map0 ----
    const float4* f4 = (const float4*)(feats + (size_t)p * DIM);
    float4 x[16];
    float n2 = 0.f;
    #pragma unroll
    for (int k = 0; k < 16; k++) {
        float4 t = f4[k];
        t.x *= IMAGE_ALPHA; t.y *= IMAGE_ALPHA; t.z *= IMAGE_ALPHA; t.w *= IMAGE_ALPHA;
        x[k] = t;
        n2 += t.x*t.x + t.y*t.y + t.z*t.z + t.w*t.w;
    }
    float rc = sqrtf(n2);
    float sh = sinhf(fminf(fmaxf(rc, EPSF), SINH_MAXF));
    float sc = sh / fmaxf(rc, EPSF);
    #pragma unroll
    for (int k = 0; k < 16; k++) { x[k].x *= sc; x[k].y *= sc; x[k].z *= sc; x[k].w *= sc; }
    float xt = sqrtf(1.0f + sc * sc * n2);   // image time coordinate

    int lab = labels[p];

    // ---- class loop: online logsumexp over logits = -SCALE*acosh(c_xyl) ----
    const float4* txt4 = (const float4*)(wsro + TXT_OFF);
    const float* ytime = wsro + YT_OFF;
    float m = -INFINITY, s = 0.f, cxl_lab = 0.f, l_lab = 0.f;
    for (int c = 0; c < NCLS; c++) {
        float d0 = 0.f, d1 = 0.f, d2 = 0.f, d3 = 0.f;
        #pragma unroll
        for (int k = 0; k < 16; k++) {
            float4 t = txt4[c * 16 + k];
            d0 = fmaf(x[k].x, t.x, d0);
            d1 = fmaf(x[k].y, t.y, d1);
            d2 = fmaf(x[k].z, t.z, d2);
            d3 = fmaf(x[k].w, t.w, d3);
        }
        float dot = (d0 + d1) + (d2 + d3);
        float cxl = fmaf(xt, ytime[c], -dot);          // x_time*y_time - dot >= 1
        float z = fmaxf(cxl, 1.0f + EPSF);
        float dist = __logf(z + sqrtf(fmaf(z, z, -1.0f)));  // acosh, z >> 1 regime
        float l = -LOGIT_SCALE * dist;
        bool is_lab = (c == lab);
        cxl_lab = is_lab ? cxl : cxl_lab;
        l_lab   = is_lab ? l   : l_lab;
        float nm = fmaxf(m, l);
        s = s * __expf(m - nm) + __expf(l - nm);
        m = nm;
    }
    float nll = (m + __logf(s)) - l_lab;

    // ---- entailment: oxy_angle(proto, img) with x=proto, y=img ----
    float pt = ytime[lab];          // proto time
    float pn = wsro[XN_OFF + lab];  // ||proto||
    float ap = wsro[AP_OFF + lab];  // half-aperture
    float cxy = -cxl_lab;           // oxy c_xyl = dot - pt*xt
    float num = fmaf(cxy, pt, xt);  // y_time + c_xyl*x_time
    float den = pn * sqrtf(fmaxf(fmaf(cxl_lab, cxl_lab, -1.0f), 0.f));
    float ain = num / (den + EPSF);
    ain = fminf(fmaxf(ain, -1.0f + EPSF), 1.0f - EPSF);
    float angle = acosf(ain);
    float ent = fmaxf(angle - ap, 0.f);

    // ---- masked accumulate ----
    float valid = mask[p] ? 0.f : 1.f;
    float v_nll = nll * valid, v_ent = ent * valid;

    #pragma unroll
    for (int o = 32; o >= 1; o >>= 1) {
        v_nll += __shfl_down(v_nll, o, 64);
        v_ent += __shfl_down(v_ent, o, 64);
        valid += __shfl_down(valid, o, 64);
    }
    __shared__ float red[3][4];
    int wid = threadIdx.x >> 6, lane = threadIdx.x & 63;
    if (lane == 0) { red[0][wid] = v_nll; red[1][wid] = v_ent; red[2][wid] = valid; }
    __syncthreads();
    if (threadIdx.x == 0) {
        float a = 0.f, b = 0.f, cn = 0.f;
        #pragma unroll
        for (int w = 0; w < 4; w++) { a += red[0][w]; b += red[1][w]; cn += red[2][w]; }
        atomicAdd(&acc[0], a);
        atomicAdd(&acc[1], b);
        atomicAdd(&acc[2], cn);
    }
}

__global__ void final_kernel(const float* acc, float* out) {
    float n = fmaxf(acc[2], 1.0f);
    out[0] = acc[0] / n + ENTAIL_WEIGHT * (acc[1] / n);
}

extern "C" void kernel_launch(void* const* d_in, const int* in_sizes, int n_in,
                              void* d_out, int out_size, void* d_ws, size_t ws_size,
                              hipStream_t stream) {
    const float* feats  = (const float*)d_in[0];
    const float* protos = (const float*)d_in[1];
    const int* labels   = (const int*)d_in[2];
    const unsigned char* mask = (const unsigned char*)d_in[3];  // numpy bool = 1 byte
    float* ws = (float*)d_ws;

    hipMemsetAsync(ws, 0, 16 * sizeof(float), stream);
    proto_kernel<<<NCLS, DIM, 0, stream>>>(protos, ws);

    int npix = in_sizes[2];                 // B*H*W = 524288
    int nblk = npix / 256;
    main_kernel<<<nblk, 256, 0, stream>>>(feats, labels, mask, ws, ws);
    final_kernel<<<1, 1, 0, stream>>>(ws, (float*)d_out);
}